// Round 7
// baseline (112.228 us; speedup 1.0000x reference)
//
#include <hip/hip_runtime.h>
#include <math.h>
#include <float.h>

// Problem constants (match reference)
#define BATCH 4
#define KCLS 16
#define NSRC 4096
#define NTGT 16384

// geometry (R4-verified): 256 threads = 4 waves; 8 targets/lane -> 512
// targets/block; SPLITS=16 -> chunk=256 sources; grid = 4*32*16 = 2048.
// R7 change: nn tracks MIN VALUE ONLY (drops the cmp+2*cndmask index select:
// 8 -> ~5.5 VALU/pair). Index recovery happens in gate via an exact,
// self-contained tie-broken argmin re-scan of the single winning chunk.
// Unlike R5 (failed), there is NO cross-kernel equality matching and NO
// ballot/ffs: every selection is a lexicographic (value,index) min.
#define THREADS 256
#define WAVES 4
#define TPL 8                               // targets per lane
#define TGT_PER_BLOCK 512                   // 64 lanes * TPL

// workspace: f32 part_min[B][SPLITS][NTGT] (4 MB @ SPLITS=16). No init
// needed: every slot is written unconditionally.

// total-order map: monotone wrt float '<' (handles negatives); verified in
// R1-R4 (same mapping used by the u64-packed argmin).
__device__ __forceinline__ unsigned ordf(float v) {
    unsigned u = __float_as_uint(v);
    return (u & 0x80000000u) ? ~u : (u | 0x80000000u);
}

// wave-wide lexicographic min of packed (ord<<32 | idx) via butterfly.
__device__ __forceinline__ unsigned long long wave_min_u64(unsigned long long p) {
#pragma unroll
    for (int m = 1; m < 64; m <<= 1) {
        unsigned long long o = __shfl_xor(p, m, 64);
        p = (o < p) ? o : p;
    }
    return p;
}

// ---------------------------------------------------------------------------
// nn_kernel<SPLITS>: per-(target, chunk) MIN of d2 (value only). Bit-exact
// d2 chain (verified absmax=0.0 across R0-R4/R6):
//   ss/tt: squares rounded individually, then sequential sum
//   dot  : rn(tx*sx); fma(ty,sy,.); fma(tz,sz,.)
//   d2   : fma(-2, dot, rn(tt+ss))
// fminf is exact and order-independent (no NaNs; +/-0 compare equal), so the
// chunk-min VALUE equals the tie-broken scan's best value numerically.
// ---------------------------------------------------------------------------
template <int SPLITS>
__global__ __launch_bounds__(THREADS) void nn_kernel(
    const float* __restrict__ source_pos,   // [B, 3, NS]
    const float* __restrict__ target_pos,   // [B, 3, NT]
    float* __restrict__ part_min)           // [B][SPLITS][NTGT]
{
    constexpr int CHUNK = NSRC / SPLITS;    // 256 (S=16) / 512 (S=8)
    constexpr int STRIPE = CHUNK / WAVES;   // 64 / 128 per wave

    // 16 KB: stage uses first CHUNK float4s; aliased after the scan as
    // smin[4][512] (8 KB).
    __shared__ float4 ls[1024];

    int tid = threadIdx.x;
    int lane = tid & 63;
    int wave = tid >> 6;                    // 0..3

    constexpr int BPB = (NTGT / TGT_PER_BLOCK) * SPLITS;
    int b = blockIdx.x / BPB;
    int rem = blockIdx.x % BPB;
    int tg = rem / SPLITS;
    int split = rem % SPLITS;
    int tbase = tg * TGT_PER_BLOCK;
    int cg = split * CHUNK;                 // this block's source-chunk base

    // stage chunk (coalesced x/y/z streams)
    const float* sxp = source_pos + (size_t)b * 3 * NSRC;
    const float* syp = sxp + NSRC;
    const float* szp = sxp + 2 * NSRC;
#pragma unroll
    for (int r = 0; r < (CHUNK + THREADS - 1) / THREADS; ++r) {
        int s = r * THREADS + tid;
        if (s < CHUNK) {
            float x = sxp[cg + s], y = syp[cg + s], z = szp[cg + s];
            float ss = __fadd_rn(__fadd_rn(__fmul_rn(x, x), __fmul_rn(y, y)),
                                 __fmul_rn(z, z));
            ls[s] = make_float4(x, y, z, ss);
        }
    }

    // eight targets per lane (coalesced loads)
    const float* tp = target_pos + (size_t)b * 3 * NTGT;
    float tx[TPL], ty[TPL], tz[TPL], tt[TPL];
#pragma unroll
    for (int j = 0; j < TPL; ++j) {
        int t = tbase + 64 * j + lane;
        tx[j] = tp[t]; ty[j] = tp[NTGT + t]; tz[j] = tp[2 * NTGT + t];
        tt[j] = __fadd_rn(__fadd_rn(__fmul_rn(tx[j], tx[j]),
                                    __fmul_rn(ty[j], ty[j])),
                          __fmul_rn(tz[j], tz[j]));
    }

    __syncthreads();

    int lbase = wave * STRIPE;
    float best[TPL];
#pragma unroll
    for (int j = 0; j < TPL; ++j) best[j] = FLT_MAX;

    // two sources per step; nested fminf may fuse to v_min3_f32 (exact either
    // way: min is associative/commutative on non-NaN data).
#pragma unroll 4
    for (int i = 0; i < STRIPE; i += 2) {
        float4 fa = ls[lbase + i];          // wave-uniform -> LDS broadcast
        float4 fb = ls[lbase + i + 1];
#pragma unroll
        for (int j = 0; j < TPL; ++j) {
            float aa = __fmul_rn(tx[j], fa.x);
            aa = __fmaf_rn(ty[j], fa.y, aa);
            aa = __fmaf_rn(tz[j], fa.z, aa);
            float d2a = __fmaf_rn(-2.0f, aa, __fadd_rn(tt[j], fa.w));
            float ab = __fmul_rn(tx[j], fb.x);
            ab = __fmaf_rn(ty[j], fb.y, ab);
            ab = __fmaf_rn(tz[j], fb.z, ab);
            float d2b = __fmaf_rn(-2.0f, ab, __fadd_rn(tt[j], fb.w));
            best[j] = fminf(fminf(d2a, d2b), best[j]);
        }
    }

    __syncthreads();                        // done READING ls before aliasing

    // cross-wave fmin combine (order-independent, exact)
    float* smin = (float*)ls;
#pragma unroll
    for (int j = 0; j < TPL; ++j)
        smin[wave * TGT_PER_BLOCK + 64 * j + lane] = best[j];
    __syncthreads();

#pragma unroll
    for (int r = 0; r < TGT_PER_BLOCK / THREADS; ++r) {
        int t = r * THREADS + tid;
        float m = smin[t];
#pragma unroll
        for (int w = 1; w < WAVES; ++w)
            m = fminf(m, smin[w * TGT_PER_BLOCK + t]);
        part_min[((size_t)b * SPLITS + split) * NTGT + tbase + t] = m;
    }
}

// ---------------------------------------------------------------------------
// gate_kernel<SPLITS>: ONE WAVE per target; no equality matching anywhere.
//  1) (m, ws) = lex-min over packed (ord(chunk_min[s]), s): earliest split
//     attaining the global min. chunk mins are exact true mins (nn chain ==
//     verified np chain), so ws contains np's first-attaining index.
//  2) exact tie-broken argmin re-scan of chunk ws (256 sources): per-lane
//     strict-'<' scan (ascending idx within lane), then cross-lane lex-min
//     of packed (ord(bestv), idx). == np.argmin tie-break, self-contained.
//  3) 16-way strided max over sem_logits (verified ascending fmaxf chain),
//     sigmoid, lane-0 store.
// ---------------------------------------------------------------------------
template <int SPLITS>
__global__ __launch_bounds__(256) void gate_kernel(
    const float* __restrict__ part_min,           // [B][SPLITS][NTGT]
    const float* __restrict__ source_pos,         // [B, 3, NS]
    const float* __restrict__ target_pos,         // [B, 3, NT]
    const float* __restrict__ sem_logits,         // [B, K, NS]
    float* __restrict__ out)                      // [B*NT]
{
    constexpr int CHUNK = NSRC / SPLITS;

    int gt = blockIdx.x * 4 + (threadIdx.x >> 6); // wave-per-target
    int lane = threadIdx.x & 63;
    int b = gt >> 14;                             // NTGT == 16384
    int t = gt & (NTGT - 1);

    // 1) earliest-min split via lex u64 min (no equality compare)
    const float* pm = part_min + (size_t)b * SPLITS * NTGT + t;
    unsigned long long pk = ~0ull;
    if (lane < SPLITS) {
        float v = pm[(size_t)lane * NTGT];
        pk = ((unsigned long long)ordf(v) << 32) | (unsigned)lane;
    }
    pk = wave_min_u64(pk);
    int ws = (int)(pk & 0xFFFFFFFFull);
    int cg = ws * CHUNK;

    // target coords (uniform) + exact tt chain
    const float* tp = target_pos + (size_t)b * 3 * NTGT;
    float tx = tp[t], ty = tp[NTGT + t], tz = tp[2 * NTGT + t];
    float tt = __fadd_rn(__fadd_rn(__fmul_rn(tx, tx), __fmul_rn(ty, ty)),
                         __fmul_rn(tz, tz));

    // 2) exact tie-broken argmin over the winning chunk (coalesced rounds)
    const float* sxp = source_pos + (size_t)b * 3 * NSRC;
    const float* syp = sxp + NSRC;
    const float* szp = sxp + 2 * NSRC;
    float bv = FLT_MAX;
    int bi = 0;
#pragma unroll
    for (int r = 0; r < CHUNK / 64; ++r) {
        int s = cg + r * 64 + lane;
        float x = sxp[s], y = syp[s], z = szp[s];
        float ss = __fadd_rn(__fadd_rn(__fmul_rn(x, x), __fmul_rn(y, y)),
                             __fmul_rn(z, z));
        float acc = __fmul_rn(tx, x);
        acc = __fmaf_rn(ty, y, acc);
        acc = __fmaf_rn(tz, z, acc);
        float d2 = __fmaf_rn(-2.0f, acc, __fadd_rn(tt, ss));
        if (d2 < bv) { bv = d2; bi = s; }         // strict '<': first idx wins
    }
    unsigned long long p2 =
        ((unsigned long long)ordf(bv) << 32) | (unsigned)bi;
    p2 = wave_min_u64(p2);                        // lex (value, index) min
    int mi = (int)(p2 & 0xFFFFFFFFull);

    // 3) gather (uniform idx) + sigmoid
    const float* lg = sem_logits + (size_t)b * KCLS * NSRC + mi;
    float mm = lg[0];
#pragma unroll
    for (int k = 1; k < KCLS; ++k) mm = fmaxf(mm, lg[(size_t)k * NSRC]);
    if (lane == 0) out[gt] = 1.0f / (1.0f + expf(-mm));
}

extern "C" void kernel_launch(void* const* d_in, const int* in_sizes, int n_in,
                              void* d_out, int out_size, void* d_ws, size_t ws_size,
                              hipStream_t stream) {
    const float* sem_logits = (const float*)d_in[0];   // [B,K,NS] fp32
    const float* source_pos = (const float*)d_in[1];   // [B,3,NS] fp32
    const float* target_pos = (const float*)d_in[2];   // [B,3,NT] fp32
    float* out = (float*)d_out;                        // [B,NT,1] fp32

    float* part_min = (float*)d_ws;

    const size_t need16 = (size_t)BATCH * 16 * NTGT * 4;   // 4 MB
    if (ws_size >= need16) {
        nn_kernel<16><<<BATCH * (NTGT / TGT_PER_BLOCK) * 16, THREADS, 0, stream>>>(
            source_pos, target_pos, part_min);
        gate_kernel<16><<<(BATCH * NTGT) / 4, 256, 0, stream>>>(
            part_min, source_pos, target_pos, sem_logits, out);
    } else {
        nn_kernel<8><<<BATCH * (NTGT / TGT_PER_BLOCK) * 8, THREADS, 0, stream>>>(
            source_pos, target_pos, part_min);
        gate_kernel<8><<<(BATCH * NTGT) / 4, 256, 0, stream>>>(
            part_min, source_pos, target_pos, sem_logits, out);
    }
}

// Round 8
// 96.114 us; speedup vs baseline: 1.1677x; 1.1677x over previous
//
#include <hip/hip_runtime.h>
#include <math.h>
#include <float.h>

// Problem constants (match reference)
#define BATCH 4
#define KCLS 16
#define NSRC 4096
#define NTGT 16384

// geometry (R4-verified): 256 threads = 4 waves; 8 targets/lane -> 512
// targets/block; SPLITS=16 -> chunk=256 sources; grid = 4*32*16 = 2048.
// R8: GROUP-GRANULAR argmin. Inner loop tracks (min value, group-of-8 base):
// exact 7-fminf tree per 8 sources + one strict-'<' (cmp+2 cndmask) update
// per group => 6.25 VALU/pair vs R4's 8. The exact index is recovered in
// gate by an exact strict-'<' argmin over the winning 8-source group
// (self-contained, no cross-kernel equality matching, no ballots).
#define THREADS 256
#define WAVES 4
#define TPL 8                               // targets per lane
#define TGT_PER_BLOCK 512                   // 64 lanes * TPL
#define GRP 8                               // sources per index-group

// workspace: u64 part[B][SPLITS][NTGT] packed (ord(min)<<32 | group_base)
// (8 MB @ SPLITS=16). No init needed: every slot written unconditionally.

// total-order map: monotone wrt float '<' (handles negatives); verified R1-R6.
__device__ __forceinline__ unsigned ordf(float v) {
    unsigned u = __float_as_uint(v);
    return (u & 0x80000000u) ? ~u : (u | 0x80000000u);
}

// ---------------------------------------------------------------------------
// nn_kernel<SPLITS>: per-(target, chunk) (min d2, earliest group-of-8 base).
// Bit-exact d2 chain (verified absmax=0.0 across R0-R4/R6):
//   ss/tt: squares rounded individually, then sequential sum
//   dot  : rn(tx*sx); fma(ty,sy,.); fma(tz,sz,.)
//   d2   : fma(-2, dot, rn(tt+ss))
// Group min via fminf tree is EXACT (min of non-NaN floats is associative/
// commutative). Ascending-group strict-'<' update => recorded group is the
// FIRST group attaining the stripe min. Cross-wave combine: lexicographic
// u64 (ord<<32|gbase) min over ascending stripes => earliest group attaining
// the block min — matches np.argmin's first-index tie-break at group level.
// ---------------------------------------------------------------------------
template <int SPLITS>
__global__ __launch_bounds__(THREADS) void nn_kernel(
    const float* __restrict__ source_pos,   // [B, 3, NS]
    const float* __restrict__ target_pos,   // [B, 3, NT]
    unsigned long long* __restrict__ part)  // [B][SPLITS][NTGT]
{
    constexpr int CHUNK = NSRC / SPLITS;    // 256 (S=16) / 512 (S=8)
    constexpr int STRIPE = CHUNK / WAVES;   // 64 / 128 per wave
    constexpr int NGRP = STRIPE / GRP;      // 8 / 16 groups per stripe

    // 16 KB: stage uses first CHUNK float4s; aliased after the scan as
    // u64 sbuf[4][512] (16 KB exactly).
    __shared__ float4 ls[1024];

    int tid = threadIdx.x;
    int lane = tid & 63;
    int wave = tid >> 6;                    // 0..3

    constexpr int BPB = (NTGT / TGT_PER_BLOCK) * SPLITS;
    int b = blockIdx.x / BPB;
    int rem = blockIdx.x % BPB;
    int tg = rem / SPLITS;
    int split = rem % SPLITS;
    int tbase = tg * TGT_PER_BLOCK;
    int cg = split * CHUNK;                 // this block's source-chunk base

    // stage chunk (coalesced x/y/z streams)
    const float* sxp = source_pos + (size_t)b * 3 * NSRC;
    const float* syp = sxp + NSRC;
    const float* szp = sxp + 2 * NSRC;
#pragma unroll
    for (int r = 0; r < (CHUNK + THREADS - 1) / THREADS; ++r) {
        int s = r * THREADS + tid;
        if (s < CHUNK) {
            float x = sxp[cg + s], y = syp[cg + s], z = szp[cg + s];
            float ss = __fadd_rn(__fadd_rn(__fmul_rn(x, x), __fmul_rn(y, y)),
                                 __fmul_rn(z, z));
            ls[s] = make_float4(x, y, z, ss);
        }
    }

    // eight targets per lane (coalesced loads)
    const float* tp = target_pos + (size_t)b * 3 * NTGT;
    float tx[TPL], ty[TPL], tz[TPL], tt[TPL];
#pragma unroll
    for (int j = 0; j < TPL; ++j) {
        int t = tbase + 64 * j + lane;
        tx[j] = tp[t]; ty[j] = tp[NTGT + t]; tz[j] = tp[2 * NTGT + t];
        tt[j] = __fadd_rn(__fadd_rn(__fmul_rn(tx[j], tx[j]),
                                    __fmul_rn(ty[j], ty[j])),
                          __fmul_rn(tz[j], tz[j]));
    }

    __syncthreads();

    int lbase = wave * STRIPE;
    int gbase = cg + lbase;                 // stripe's global source base
    float best[TPL];
    int bg[TPL];
#pragma unroll
    for (int j = 0; j < TPL; ++j) { best[j] = FLT_MAX; bg[j] = gbase; }

#pragma unroll 2
    for (int g = 0; g < NGRP; ++g) {
        float4 f[GRP];
#pragma unroll
        for (int k = 0; k < GRP; ++k) f[k] = ls[lbase + g * GRP + k];
        int grpbase = gbase + g * GRP;
#pragma unroll
        for (int j = 0; j < TPL; ++j) {
            float d[GRP];
#pragma unroll
            for (int k = 0; k < GRP; ++k) {
                float acc = __fmul_rn(tx[j], f[k].x);
                acc = __fmaf_rn(ty[j], f[k].y, acc);
                acc = __fmaf_rn(tz[j], f[k].z, acc);
                d[k] = __fmaf_rn(-2.0f, acc, __fadd_rn(tt[j], f[k].w));
            }
            // exact group min (order-independent on non-NaN data)
            float m01 = fminf(d[0], d[1]);
            float m23 = fminf(d[2], d[3]);
            float m45 = fminf(d[4], d[5]);
            float m67 = fminf(d[6], d[7]);
            float gm = fminf(fminf(m01, m23), fminf(m45, m67));
            // strict '<', ascending groups: first group attaining the min
            if (gm < best[j]) { best[j] = gm; bg[j] = grpbase; }
        }
    }

    __syncthreads();                        // done READING ls before aliasing

    // cross-wave combine: lexicographic u64 (ord(value)<<32 | group_base)
    // min over ascending waves == earliest group attaining the block min.
    unsigned long long* sp64 = (unsigned long long*)ls;
#pragma unroll
    for (int j = 0; j < TPL; ++j)
        sp64[wave * TGT_PER_BLOCK + 64 * j + lane] =
            ((unsigned long long)ordf(best[j]) << 32) | (unsigned)bg[j];
    __syncthreads();

#pragma unroll
    for (int r = 0; r < TGT_PER_BLOCK / THREADS; ++r) {
        int t = r * THREADS + tid;
        unsigned long long m = sp64[t];
#pragma unroll
        for (int w = 1; w < WAVES; ++w) {
            unsigned long long v = sp64[w * TGT_PER_BLOCK + t];
            if (v < m) m = v;
        }
        part[((size_t)b * SPLITS + split) * NTGT + tbase + t] = m;
    }
}

// ---------------------------------------------------------------------------
// gate_kernel<SPLITS>: thread-per-target (R4's cheap shape).
//  1) u64 lex-min over the SPLITS partials (ascending, strict '<') ==
//     earliest group-of-8 attaining the global min.
//  2) exact strict-'<' argmin re-scan of those 8 sources with the verified
//     d2 chain => first global index attaining the min (np.argmin tie-break).
//     Self-contained: no equality matching against nn's values anywhere.
//  3) verified 16-way strided ascending fmaxf over sem_logits + sigmoid.
// ---------------------------------------------------------------------------
template <int SPLITS>
__global__ __launch_bounds__(256) void gate_kernel(
    const unsigned long long* __restrict__ part,  // [B][SPLITS][NTGT]
    const float* __restrict__ source_pos,         // [B, 3, NS]
    const float* __restrict__ target_pos,         // [B, 3, NT]
    const float* __restrict__ sem_logits,         // [B, K, NS]
    float* __restrict__ out)                      // [B*NT]
{
    int gt = blockIdx.x * 256 + threadIdx.x;      // 0 .. B*NT-1
    int b = gt >> 14;                             // NTGT == 16384
    int t = gt & (NTGT - 1);

    // 1) combine split partials (coalesced in t)
    const unsigned long long* pp = part + (size_t)b * SPLITS * NTGT + t;
    unsigned long long best = pp[0];
#pragma unroll
    for (int s = 1; s < SPLITS; ++s) {
        unsigned long long v = pp[(size_t)s * NTGT];
        if (v < best) best = v;
    }
    int gbase = (int)(best & 0xFFFFFFFFull);      // winning group base

    // 2) exact argmin over the 8-source group (verified chain, strict '<')
    const float* tp = target_pos + (size_t)b * 3 * NTGT;
    float tx = tp[t], ty = tp[NTGT + t], tz = tp[2 * NTGT + t];
    float tt = __fadd_rn(__fadd_rn(__fmul_rn(tx, tx), __fmul_rn(ty, ty)),
                         __fmul_rn(tz, tz));
    const float* sxp = source_pos + (size_t)b * 3 * NSRC;
    const float* syp = sxp + NSRC;
    const float* szp = sxp + 2 * NSRC;
    float bv = FLT_MAX;
    int mi = gbase;
#pragma unroll
    for (int k = 0; k < GRP; ++k) {
        int s = gbase + k;
        float x = sxp[s], y = syp[s], z = szp[s];
        float ss = __fadd_rn(__fadd_rn(__fmul_rn(x, x), __fmul_rn(y, y)),
                             __fmul_rn(z, z));
        float acc = __fmul_rn(tx, x);
        acc = __fmaf_rn(ty, y, acc);
        acc = __fmaf_rn(tz, z, acc);
        float d2 = __fmaf_rn(-2.0f, acc, __fadd_rn(tt, ss));
        if (d2 < bv) { bv = d2; mi = s; }         // ascending: first idx wins
    }

    // 3) gather + sigmoid (verified ascending fmaxf chain)
    const float* lg = sem_logits + (size_t)b * KCLS * NSRC + mi;
    float mm = lg[0];
#pragma unroll
    for (int k = 1; k < KCLS; ++k) mm = fmaxf(mm, lg[(size_t)k * NSRC]);
    out[gt] = 1.0f / (1.0f + expf(-mm));
}

extern "C" void kernel_launch(void* const* d_in, const int* in_sizes, int n_in,
                              void* d_out, int out_size, void* d_ws, size_t ws_size,
                              hipStream_t stream) {
    const float* sem_logits = (const float*)d_in[0];   // [B,K,NS] fp32
    const float* source_pos = (const float*)d_in[1];   // [B,3,NS] fp32
    const float* target_pos = (const float*)d_in[2];   // [B,3,NT] fp32
    float* out = (float*)d_out;                        // [B,NT,1] fp32

    unsigned long long* part = (unsigned long long*)d_ws;

    const size_t need16 = (size_t)BATCH * 16 * NTGT * 8;   // 8 MB
    if (ws_size >= need16) {
        nn_kernel<16><<<BATCH * (NTGT / TGT_PER_BLOCK) * 16, THREADS, 0, stream>>>(
            source_pos, target_pos, part);
        gate_kernel<16><<<(BATCH * NTGT) / 256, 256, 0, stream>>>(
            part, source_pos, target_pos, sem_logits, out);
    } else {
        nn_kernel<8><<<BATCH * (NTGT / TGT_PER_BLOCK) * 8, THREADS, 0, stream>>>(
            source_pos, target_pos, part);
        gate_kernel<8><<<(BATCH * NTGT) / 256, 256, 0, stream>>>(
            part, source_pos, target_pos, sem_logits, out);
    }
}

// Round 9
// 96.097 us; speedup vs baseline: 1.1679x; 1.0002x over previous
//
#include <hip/hip_runtime.h>
#include <math.h>
#include <float.h>

// Problem constants (match reference)
#define BATCH 4
#define KCLS 16
#define NSRC 4096
#define NTGT 16384

// geometry (R4-verified): 256 threads = 4 waves; 8 targets/lane -> 512
// targets/block; SPLITS=16 -> chunk=256 sources; grid = 4*32*16 = 2048.
// R8 (verified absmax=0.0): GROUP-GRANULAR argmin — (min value, group-of-8
// base) in nn; exact strict-'<' rescan of the 8-source group in gate.
// R9 change: group-min tree re-associated into v_min3_f32-fusable shape
// (7 -> 4 VALU per group; min is exact/associative on non-NaN data, so the
// group-min VALUE is bit-identical and all selection semantics unchanged).
// Per-pair VALU: 5 (d2 chain) + 4/8 (tree) + 3/8 (update) = 5.875 vs 6.25.
#define THREADS 256
#define WAVES 4
#define TPL 8                               // targets per lane
#define TGT_PER_BLOCK 512                   // 64 lanes * TPL
#define GRP 8                               // sources per index-group

// workspace: u64 part[B][SPLITS][NTGT] packed (ord(min)<<32 | group_base)
// (8 MB @ SPLITS=16). No init needed: every slot written unconditionally.

// total-order map: monotone wrt float '<' (handles negatives); verified R1-R8.
__device__ __forceinline__ unsigned ordf(float v) {
    unsigned u = __float_as_uint(v);
    return (u & 0x80000000u) ? ~u : (u | 0x80000000u);
}

// ---------------------------------------------------------------------------
// nn_kernel<SPLITS>: per-(target, chunk) (min d2, earliest group-of-8 base).
// Bit-exact d2 chain (verified absmax=0.0 across R0-R8):
//   ss/tt: squares rounded individually, then sequential sum
//   dot  : rn(tx*sx); fma(ty,sy,.); fma(tz,sz,.)
//   d2   : fma(-2, dot, rn(tt+ss))
// Group min via min3-shaped fminf tree is EXACT (min of non-NaN floats is
// associative/commutative — any association gives the identical bit value).
// Ascending-group strict-'<' update => recorded group is the FIRST group
// attaining the stripe min. Cross-wave combine: lexicographic u64
// (ord<<32|gbase) min over ascending stripes => earliest group attaining
// the block min — matches np.argmin's first-index tie-break at group level.
// ---------------------------------------------------------------------------
template <int SPLITS>
__global__ __launch_bounds__(THREADS) void nn_kernel(
    const float* __restrict__ source_pos,   // [B, 3, NS]
    const float* __restrict__ target_pos,   // [B, 3, NT]
    unsigned long long* __restrict__ part)  // [B][SPLITS][NTGT]
{
    constexpr int CHUNK = NSRC / SPLITS;    // 256 (S=16) / 512 (S=8)
    constexpr int STRIPE = CHUNK / WAVES;   // 64 / 128 per wave
    constexpr int NGRP = STRIPE / GRP;      // 8 / 16 groups per stripe

    // 16 KB: stage uses first CHUNK float4s; aliased after the scan as
    // u64 sbuf[4][512] (16 KB exactly).
    __shared__ float4 ls[1024];

    int tid = threadIdx.x;
    int lane = tid & 63;
    int wave = tid >> 6;                    // 0..3

    constexpr int BPB = (NTGT / TGT_PER_BLOCK) * SPLITS;
    int b = blockIdx.x / BPB;
    int rem = blockIdx.x % BPB;
    int tg = rem / SPLITS;
    int split = rem % SPLITS;
    int tbase = tg * TGT_PER_BLOCK;
    int cg = split * CHUNK;                 // this block's source-chunk base

    // stage chunk (coalesced x/y/z streams)
    const float* sxp = source_pos + (size_t)b * 3 * NSRC;
    const float* syp = sxp + NSRC;
    const float* szp = sxp + 2 * NSRC;
#pragma unroll
    for (int r = 0; r < (CHUNK + THREADS - 1) / THREADS; ++r) {
        int s = r * THREADS + tid;
        if (s < CHUNK) {
            float x = sxp[cg + s], y = syp[cg + s], z = szp[cg + s];
            float ss = __fadd_rn(__fadd_rn(__fmul_rn(x, x), __fmul_rn(y, y)),
                                 __fmul_rn(z, z));
            ls[s] = make_float4(x, y, z, ss);
        }
    }

    // eight targets per lane (coalesced loads)
    const float* tp = target_pos + (size_t)b * 3 * NTGT;
    float tx[TPL], ty[TPL], tz[TPL], tt[TPL];
#pragma unroll
    for (int j = 0; j < TPL; ++j) {
        int t = tbase + 64 * j + lane;
        tx[j] = tp[t]; ty[j] = tp[NTGT + t]; tz[j] = tp[2 * NTGT + t];
        tt[j] = __fadd_rn(__fadd_rn(__fmul_rn(tx[j], tx[j]),
                                    __fmul_rn(ty[j], ty[j])),
                          __fmul_rn(tz[j], tz[j]));
    }

    __syncthreads();

    int lbase = wave * STRIPE;
    int gbase = cg + lbase;                 // stripe's global source base
    float best[TPL];
    int bg[TPL];
#pragma unroll
    for (int j = 0; j < TPL; ++j) { best[j] = FLT_MAX; bg[j] = gbase; }

#pragma unroll 2
    for (int g = 0; g < NGRP; ++g) {
        float4 f[GRP];
#pragma unroll
        for (int k = 0; k < GRP; ++k) f[k] = ls[lbase + g * GRP + k];
        int grpbase = gbase + g * GRP;
#pragma unroll
        for (int j = 0; j < TPL; ++j) {
            float d[GRP];
#pragma unroll
            for (int k = 0; k < GRP; ++k) {
                float acc = __fmul_rn(tx[j], f[k].x);
                acc = __fmaf_rn(ty[j], f[k].y, acc);
                acc = __fmaf_rn(tz[j], f[k].z, acc);
                d[k] = __fmaf_rn(-2.0f, acc, __fadd_rn(tt[j], f[k].w));
            }
            // exact group min, v_min3-fusable shape (4 instrs, depth 3):
            //   m0 = min3(d0,d1,d2); m1 = min3(d3,d4,d5);
            //   m2 = min3(d6,d7,m0); gm = min(m1,m2)
            float m0 = fminf(fminf(d[0], d[1]), d[2]);
            float m1 = fminf(fminf(d[3], d[4]), d[5]);
            float m2 = fminf(fminf(d[6], d[7]), m0);
            float gm = fminf(m1, m2);
            // strict '<', ascending groups: first group attaining the min
            if (gm < best[j]) { best[j] = gm; bg[j] = grpbase; }
        }
    }

    __syncthreads();                        // done READING ls before aliasing

    // cross-wave combine: lexicographic u64 (ord(value)<<32 | group_base)
    // min over ascending waves == earliest group attaining the block min.
    unsigned long long* sp64 = (unsigned long long*)ls;
#pragma unroll
    for (int j = 0; j < TPL; ++j)
        sp64[wave * TGT_PER_BLOCK + 64 * j + lane] =
            ((unsigned long long)ordf(best[j]) << 32) | (unsigned)bg[j];
    __syncthreads();

#pragma unroll
    for (int r = 0; r < TGT_PER_BLOCK / THREADS; ++r) {
        int t = r * THREADS + tid;
        unsigned long long m = sp64[t];
#pragma unroll
        for (int w = 1; w < WAVES; ++w) {
            unsigned long long v = sp64[w * TGT_PER_BLOCK + t];
            if (v < m) m = v;
        }
        part[((size_t)b * SPLITS + split) * NTGT + tbase + t] = m;
    }
}

// ---------------------------------------------------------------------------
// gate_kernel<SPLITS>: thread-per-target (R4's cheap shape).
//  1) u64 lex-min over the SPLITS partials (ascending, strict '<') ==
//     earliest group-of-8 attaining the global min.
//  2) exact strict-'<' argmin re-scan of those 8 sources with the verified
//     d2 chain => first global index attaining the min (np.argmin tie-break).
//     Self-contained: no equality matching against nn's values anywhere.
//  3) max over sem_logits re-associated into a max3-fusable tree — exact
//     (max of non-NaN floats is associative/commutative) — + sigmoid.
// ---------------------------------------------------------------------------
template <int SPLITS>
__global__ __launch_bounds__(256) void gate_kernel(
    const unsigned long long* __restrict__ part,  // [B][SPLITS][NTGT]
    const float* __restrict__ source_pos,         // [B, 3, NS]
    const float* __restrict__ target_pos,         // [B, 3, NT]
    const float* __restrict__ sem_logits,         // [B, K, NS]
    float* __restrict__ out)                      // [B*NT]
{
    int gt = blockIdx.x * 256 + threadIdx.x;      // 0 .. B*NT-1
    int b = gt >> 14;                             // NTGT == 16384
    int t = gt & (NTGT - 1);

    // 1) combine split partials (coalesced in t)
    const unsigned long long* pp = part + (size_t)b * SPLITS * NTGT + t;
    unsigned long long best = pp[0];
#pragma unroll
    for (int s = 1; s < SPLITS; ++s) {
        unsigned long long v = pp[(size_t)s * NTGT];
        if (v < best) best = v;
    }
    int gbase = (int)(best & 0xFFFFFFFFull);      // winning group base

    // 2) exact argmin over the 8-source group (verified chain, strict '<')
    const float* tp = target_pos + (size_t)b * 3 * NTGT;
    float tx = tp[t], ty = tp[NTGT + t], tz = tp[2 * NTGT + t];
    float tt = __fadd_rn(__fadd_rn(__fmul_rn(tx, tx), __fmul_rn(ty, ty)),
                         __fmul_rn(tz, tz));
    const float* sxp = source_pos + (size_t)b * 3 * NSRC;
    const float* syp = sxp + NSRC;
    const float* szp = sxp + 2 * NSRC;
    float bv = FLT_MAX;
    int mi = gbase;
#pragma unroll
    for (int k = 0; k < GRP; ++k) {
        int s = gbase + k;
        float x = sxp[s], y = syp[s], z = szp[s];
        float ss = __fadd_rn(__fadd_rn(__fmul_rn(x, x), __fmul_rn(y, y)),
                             __fmul_rn(z, z));
        float acc = __fmul_rn(tx, x);
        acc = __fmaf_rn(ty, y, acc);
        acc = __fmaf_rn(tz, z, acc);
        float d2 = __fmaf_rn(-2.0f, acc, __fadd_rn(tt, ss));
        if (d2 < bv) { bv = d2; mi = s; }         // ascending: first idx wins
    }

    // 3) gather + max3-shaped exact max tree + sigmoid
    const float* lg = sem_logits + (size_t)b * KCLS * NSRC + mi;
    float l[KCLS];
#pragma unroll
    for (int k = 0; k < KCLS; ++k) l[k] = lg[(size_t)k * NSRC];
    float a0 = fmaxf(fmaxf(l[0], l[1]), l[2]);
    float a1 = fmaxf(fmaxf(l[3], l[4]), l[5]);
    float a2 = fmaxf(fmaxf(l[6], l[7]), l[8]);
    float a3 = fmaxf(fmaxf(l[9], l[10]), l[11]);
    float a4 = fmaxf(fmaxf(l[12], l[13]), l[14]);
    float b0 = fmaxf(fmaxf(a0, a1), a2);
    float b1 = fmaxf(fmaxf(a3, a4), l[15]);
    float mm = fmaxf(b0, b1);
    out[gt] = 1.0f / (1.0f + expf(-mm));
}

extern "C" void kernel_launch(void* const* d_in, const int* in_sizes, int n_in,
                              void* d_out, int out_size, void* d_ws, size_t ws_size,
                              hipStream_t stream) {
    const float* sem_logits = (const float*)d_in[0];   // [B,K,NS] fp32
    const float* source_pos = (const float*)d_in[1];   // [B,3,NS] fp32
    const float* target_pos = (const float*)d_in[2];   // [B,3,NT] fp32
    float* out = (float*)d_out;                        // [B,NT,1] fp32

    unsigned long long* part = (unsigned long long*)d_ws;

    const size_t need16 = (size_t)BATCH * 16 * NTGT * 8;   // 8 MB
    if (ws_size >= need16) {
        nn_kernel<16><<<BATCH * (NTGT / TGT_PER_BLOCK) * 16, THREADS, 0, stream>>>(
            source_pos, target_pos, part);
        gate_kernel<16><<<(BATCH * NTGT) / 256, 256, 0, stream>>>(
            part, source_pos, target_pos, sem_logits, out);
    } else {
        nn_kernel<8><<<BATCH * (NTGT / TGT_PER_BLOCK) * 8, THREADS, 0, stream>>>(
            source_pos, target_pos, part);
        gate_kernel<8><<<(BATCH * NTGT) / 256, 256, 0, stream>>>(
            part, source_pos, target_pos, sem_logits, out);
    }
}